// Round 4
// baseline (432.623 us; speedup 1.0000x reference)
//
#include <hip/hip_runtime.h>
#include <math.h>

#define EPSF 1e-5f

// Pin a float in a VGPR: makes the value opaque so the compiler cannot
// rematerialize the load that produced it (forces true register residency).
#define PIN(v) asm volatile("" : "+v"(v))

// ---------------- K1: node transforms  P = x @ {Wf_i, Ws_i, Wf_j, Ws_j} (+bias) ----
__global__ __launch_bounds__(256, 4) void node_gemm(
    const float* __restrict__ x, const float* __restrict__ Wf,
    const float* __restrict__ bf, const float* __restrict__ Ws,
    const float* __restrict__ bs, float* __restrict__ Pdst,
    float* __restrict__ Psrc, int N) {
  const int lane = threadIdx.x & 63;
  const int w = threadIdx.x >> 6;
  const float* W = (w & 1) ? Ws : Wf;
  const int baseRow = (w >> 1) * 64;
  float wreg[64];
#pragma unroll
  for (int k = 0; k < 64; ++k) wreg[k] = W[(baseRow + k) * 64 + lane];
#pragma unroll
  for (int k = 0; k < 64; ++k) PIN(wreg[k]);
  float bias = 0.f;
  if (w == 0) bias = bf[lane];
  if (w == 1) bias = bs[lane];
  float* outp = (w >> 1) ? Psrc : Pdst;
  const int outOff = (w & 1) * 64;

  for (int n = blockIdx.x; n < N; n += gridDim.x) {
    const float* xr = x + (size_t)n * 64;
    float a0 = bias, a1 = 0.f, a2 = 0.f, a3 = 0.f;
#pragma unroll
    for (int k = 0; k < 64; k += 16) {
      float4 v0 = *(const float4*)(xr + k);
      float4 v1 = *(const float4*)(xr + k + 4);
      float4 v2 = *(const float4*)(xr + k + 8);
      float4 v3 = *(const float4*)(xr + k + 12);
      a0 = fmaf(v0.x, wreg[k], a0);      a0 = fmaf(v0.y, wreg[k + 1], a0);
      a0 = fmaf(v0.z, wreg[k + 2], a0);  a0 = fmaf(v0.w, wreg[k + 3], a0);
      a1 = fmaf(v1.x, wreg[k + 4], a1);  a1 = fmaf(v1.y, wreg[k + 5], a1);
      a1 = fmaf(v1.z, wreg[k + 6], a1);  a1 = fmaf(v1.w, wreg[k + 7], a1);
      a2 = fmaf(v2.x, wreg[k + 8], a2);  a2 = fmaf(v2.y, wreg[k + 9], a2);
      a2 = fmaf(v2.z, wreg[k + 10], a2); a2 = fmaf(v2.w, wreg[k + 11], a2);
      a3 = fmaf(v3.x, wreg[k + 12], a3); a3 = fmaf(v3.y, wreg[k + 13], a3);
      a3 = fmaf(v3.z, wreg[k + 14], a3); a3 = fmaf(v3.w, wreg[k + 15], a3);
    }
    outp[(size_t)n * 128 + outOff + lane] = (a0 + a1) + (a2 + a3);
  }
}

// ---------------- CSR build: histogram of dst ----------------
__global__ void hist_kernel(const int* __restrict__ ei, int* __restrict__ deg,
                            int E) {
  int i = blockIdx.x * blockDim.x + threadIdx.x;
  if (i < E) atomicAdd(&deg[ei[E + i]], 1);
}

// ---------------- CSR build: exclusive scan (single block, 16/thread) --------
__global__ __launch_bounds__(1024) void scan_kernel(
    const int* __restrict__ deg, int* __restrict__ offsets,
    int* __restrict__ cursor, int N) {
  __shared__ int wsum[16];
  __shared__ int carry_s;
  const int t = threadIdx.x;
  const int lane = t & 63;
  const int w = t >> 6;
  if (t == 0) carry_s = 0;
  __syncthreads();
  const int PER = 16;
  const int PASS = 1024 * PER;
  for (int base = 0; base < N; base += PASS) {
    const int i0 = base + t * PER;
    int d[PER];
    int s = 0;
#pragma unroll
    for (int k = 0; k < PER; ++k) {
      int idx = i0 + k;
      d[k] = (idx < N) ? deg[idx] : 0;
      s += d[k];
    }
    int sc = s;
#pragma unroll
    for (int o = 1; o < 64; o <<= 1) {
      int v = __shfl_up(sc, o);
      if (lane >= o) sc += v;
    }
    if (lane == 63) wsum[w] = sc;
    __syncthreads();
    int c = carry_s;
    int woff = 0, total = 0;
#pragma unroll
    for (int k = 0; k < 16; ++k) {
      woff += (k < w) ? wsum[k] : 0;
      total += wsum[k];
    }
    int run = c + woff + (sc - s);
#pragma unroll
    for (int k = 0; k < PER; ++k) {
      int idx = i0 + k;
      if (idx < N) { offsets[idx] = run; cursor[idx] = run; }
      run += d[k];
    }
    __syncthreads();
    if (t == 0) carry_s = c + total;
    __syncthreads();
  }
  if (t == 0) offsets[N] = carry_s;
}

// ---------------- CSR build: scatter (eattr_idx, src) pairs -----------------
__global__ void scatter_kernel(const int* __restrict__ ei,
                               int* __restrict__ cursor,
                               int2* __restrict__ epair, int E) {
  int i = blockIdx.x * blockDim.x + threadIdx.x;
  if (i < E) {
    int dst = ei[E + i];
    int pos = atomicAdd(&cursor[dst], 1);
    epair[pos] = make_int2(i, ei[i]);
  }
}

// ---------------- K2: per-node edge aggregation (atomic-free) ----------------
__global__ __launch_bounds__(256, 3) void edge_agg(
    const int* __restrict__ offsets, const int2* __restrict__ epair,
    const float* __restrict__ eattr, const float* __restrict__ Wf,
    const float* __restrict__ Ws, const float* __restrict__ Pdst,
    const float* __restrict__ Psrc, float* __restrict__ agg, int N,
    int nWaves) {
  const int lane = threadIdx.x & 63;
  const int wid = __builtin_amdgcn_readfirstlane(
      blockIdx.x * (blockDim.x >> 6) + (threadIdx.x >> 6));
  float wf[32], wsr[32];
#pragma unroll
  for (int k = 0; k < 32; ++k) {
    wf[k] = Wf[(128 + k) * 64 + lane];
    wsr[k] = Ws[(128 + k) * 64 + lane];
  }
#pragma unroll
  for (int k = 0; k < 32; ++k) { PIN(wf[k]); PIN(wsr[k]); }

  for (int n = wid; n < N; n += nWaves) {
    const int o0 = __builtin_amdgcn_readfirstlane(offsets[n]);
    const int o1 = __builtin_amdgcn_readfirstlane(offsets[n + 1]);
    const float fb = Pdst[(size_t)n * 128 + lane];
    const float sb = Pdst[(size_t)n * 128 + 64 + lane];
    float acc = 0.f;
    for (int j = o0; j < o1; ++j) {
      int2 p = epair[j];
      const int ex = __builtin_amdgcn_readfirstlane(p.x);
      const int sr = __builtin_amdgcn_readfirstlane(p.y);
      const float* er = eattr + (size_t)ex * 32;
      const float* pr = Psrc + (size_t)sr * 128;
      float f0 = fb + pr[lane];
      float s0 = sb + pr[64 + lane];
      float f1 = 0.f, f2 = 0.f, f3 = 0.f;
      float s1 = 0.f, s2 = 0.f, s3 = 0.f;
#pragma unroll
      for (int k = 0; k < 32; k += 16) {
        float4 e0 = *(const float4*)(er + k);
        float4 e1 = *(const float4*)(er + k + 4);
        float4 e2 = *(const float4*)(er + k + 8);
        float4 e3 = *(const float4*)(er + k + 12);
        f0 = fmaf(e0.x, wf[k], f0);      s0 = fmaf(e0.x, wsr[k], s0);
        f0 = fmaf(e0.y, wf[k + 1], f0);  s0 = fmaf(e0.y, wsr[k + 1], s0);
        f0 = fmaf(e0.z, wf[k + 2], f0);  s0 = fmaf(e0.z, wsr[k + 2], s0);
        f0 = fmaf(e0.w, wf[k + 3], f0);  s0 = fmaf(e0.w, wsr[k + 3], s0);
        f1 = fmaf(e1.x, wf[k + 4], f1);  s1 = fmaf(e1.x, wsr[k + 4], s1);
        f1 = fmaf(e1.y, wf[k + 5], f1);  s1 = fmaf(e1.y, wsr[k + 5], s1);
        f1 = fmaf(e1.z, wf[k + 6], f1);  s1 = fmaf(e1.z, wsr[k + 6], s1);
        f1 = fmaf(e1.w, wf[k + 7], f1);  s1 = fmaf(e1.w, wsr[k + 7], s1);
        f2 = fmaf(e2.x, wf[k + 8], f2);  s2 = fmaf(e2.x, wsr[k + 8], s2);
        f2 = fmaf(e2.y, wf[k + 9], f2);  s2 = fmaf(e2.y, wsr[k + 9], s2);
        f2 = fmaf(e2.z, wf[k + 10], f2); s2 = fmaf(e2.z, wsr[k + 10], s2);
        f2 = fmaf(e2.w, wf[k + 11], f2); s2 = fmaf(e2.w, wsr[k + 11], s2);
        f3 = fmaf(e3.x, wf[k + 12], f3); s3 = fmaf(e3.x, wsr[k + 12], s3);
        f3 = fmaf(e3.y, wf[k + 13], f3); s3 = fmaf(e3.y, wsr[k + 13], s3);
        f3 = fmaf(e3.z, wf[k + 14], f3); s3 = fmaf(e3.z, wsr[k + 14], s3);
        f3 = fmaf(e3.w, wf[k + 15], f3); s3 = fmaf(e3.w, wsr[k + 15], s3);
      }
      float f = (f0 + f1) + (f2 + f3);
      float s = (s0 + s1) + (s2 + s3);
      float sig = __builtin_amdgcn_rcpf(1.0f + __expf(-f));
      float sp = fmaxf(s, 0.f) + __logf(1.0f + __expf(-fabsf(s)));
      acc += sig * sp;
    }
    agg[(size_t)n * 64 + lane] = acc;
  }
}

// ---------------- K3: per-feature reductions over agg and x ----------------
__global__ __launch_bounds__(256) void stats_kernel(
    const float* __restrict__ agg, const float* __restrict__ x,
    float* __restrict__ stats, int N) {
  const int f = threadIdx.x & 63;
  const int sub = threadIdx.x >> 6;
  float sa = 0, sa2 = 0, sx = 0, sx2 = 0, sax = 0;
  for (int r = blockIdx.x * 4 + sub; r < N; r += gridDim.x * 4) {
    float a = agg[(size_t)r * 64 + f];
    float xv = x[(size_t)r * 64 + f];
    sa += a; sa2 += a * a; sx += xv; sx2 += xv * xv; sax += a * xv;
  }
  __shared__ float lds[4][5][64];
  lds[sub][0][f] = sa; lds[sub][1][f] = sa2; lds[sub][2][f] = sx;
  lds[sub][3][f] = sx2; lds[sub][4][f] = sax;
  __syncthreads();
  if (sub == 0) {
#pragma unroll
    for (int i = 0; i < 5; ++i) {
      float v = lds[0][i][f] + lds[1][i][f] + lds[2][i][f] + lds[3][i][f];
      atomicAdd(&stats[i * 64 + f], v);
    }
  }
}

// ---------------- K4: finalize BN affine + analytic LN stats ----------------
__global__ __launch_bounds__(64) void finalize_stats(
    const float* __restrict__ stats, const float* __restrict__ bn_w,
    const float* __restrict__ bn_b, float* __restrict__ ab, int N) {
  const int f = threadIdx.x;
  const float Nf = (float)N;
  const float invN = 1.0f / Nf;
  float Sa = stats[f], Sa2 = stats[64 + f], Sx = stats[128 + f],
        Sx2 = stats[192 + f], Sax = stats[256 + f];
  float mu = Sa * invN;
  float var = Sa2 * invN - mu * mu;
  float alpha = bn_w[f] / sqrtf(var + EPSF);
  float beta = bn_b[f] - mu * alpha;
  float Sh = alpha * Sa + Nf * beta + Sx;
  float Sh2 = alpha * alpha * Sa2 + Sx2 + Nf * beta * beta +
              2.f * alpha * Sax + 2.f * alpha * beta * Sa + 2.f * beta * Sx;
#pragma unroll
  for (int o = 32; o > 0; o >>= 1) {
    Sh += __shfl_down(Sh, o);
    Sh2 += __shfl_down(Sh2, o);
  }
  ab[f] = alpha;
  ab[64 + f] = beta;
  if (f == 0) {
    float cnt = Nf * 64.0f;
    float mean = Sh / cnt;
    float msq = Sh2 / cnt - mean * mean;
    ab[128] = mean;
    ab[129] = 1.0f / (sqrtf(fmaxf(msq, 0.f)) + EPSF);
  }
}

// ---------------- K5: BN+residual+LN+softplus, pooled into graphs ------------
__global__ __launch_bounds__(256) void node_finish(
    const float* __restrict__ agg, const float* __restrict__ x,
    const int* __restrict__ batch, const float* __restrict__ ab,
    const float* __restrict__ ln_w, const float* __restrict__ ln_b,
    float* __restrict__ add_pool, float* __restrict__ counts, int N,
    int chunk) {
  const int f = threadIdx.x & 63;
  const int sub = threadIdx.x >> 6;
  const int r0 = blockIdx.x * chunk;
  const int r1 = min(N, r0 + chunk);
  const float alpha = ab[f], beta = ab[64 + f];
  const float mean = ab[128], rden = ab[129];
  const float lw = ln_w[f] * rden;
  const float lb = ln_b[f];
  float acc = 0.f, cacc = 0.f;
  int curg = -1;
  for (int r = r0 + sub; r < r1; r += 4) {
    int g = batch[r];
    if (g != curg) {
      if (curg >= 0) {
        atomicAdd(&add_pool[(size_t)curg * 64 + f], acc);
        if (f == 0) atomicAdd(&counts[curg], cacc);
      }
      curg = g; acc = 0.f; cacc = 0.f;
    }
    float h = fmaf(alpha, agg[(size_t)r * 64 + f], beta) + x[(size_t)r * 64 + f];
    float v = (h - mean) * lw + lb;
    float sp = fmaxf(v, 0.f) + __logf(1.0f + __expf(-fabsf(v)));
    acc += sp; cacc += 1.f;
  }
  if (curg >= 0) {
    atomicAdd(&add_pool[(size_t)curg * 64 + f], acc);
    if (f == 0) atomicAdd(&counts[curg], cacc);
  }
}

// ---------------- K6: graph head ----------------
__global__ __launch_bounds__(1024) void graph_out(
    const float* __restrict__ add_pool, const float* __restrict__ counts,
    const float* __restrict__ Wl, const float* __restrict__ bl,
    const float* __restrict__ w4, const float* __restrict__ b4,
    float* __restrict__ out, int G) {
  const int t = threadIdx.x;
  const int g = t >> 1, c = t & 1;
  float cnt = fmaxf(counts[g], 1.0f);
  float inv = 1.0f / cnt;
  const float* ap = add_pool + (size_t)g * 64;
  float v = bl[c];
#pragma unroll 8
  for (int k = 0; k < 64; ++k)
    v = fmaf(ap[k], fmaf(Wl[k * 2 + c], inv, Wl[(64 + k) * 2 + c]), v);

  __shared__ float red[16];
  __shared__ float bc[2];
  float sum = v;
#pragma unroll
  for (int o = 32; o > 0; o >>= 1) sum += __shfl_down(sum, o);
  if ((t & 63) == 0) red[t >> 6] = sum;
  __syncthreads();
  if (t == 0) {
    float tot = 0;
#pragma unroll
    for (int i = 0; i < 16; ++i) tot += red[i];
    bc[0] = tot * (1.0f / 1024.0f);
  }
  __syncthreads();
  const float mean = bc[0];
  const float xc = v - mean;
  float sq = xc * xc;
  __syncthreads();
#pragma unroll
  for (int o = 32; o > 0; o >>= 1) sq += __shfl_down(sq, o);
  if ((t & 63) == 0) red[t >> 6] = sq;
  __syncthreads();
  if (t == 0) {
    float tot = 0;
#pragma unroll
    for (int i = 0; i < 16; ++i) tot += red[i];
    bc[1] = 1.0f / (sqrtf(tot * (1.0f / 1024.0f)) + EPSF);
  }
  __syncthreads();
  out[t] = xc * bc[1] * w4[c] + b4[c];
}

extern "C" void kernel_launch(void* const* d_in, const int* in_sizes, int n_in,
                              void* d_out, int out_size, void* d_ws,
                              size_t ws_size, hipStream_t stream) {
  const float* x = (const float*)d_in[0];
  const int* ei = (const int*)d_in[1];
  const float* eattr = (const float*)d_in[2];
  const int* batch = (const int*)d_in[3];
  const float* Wf = (const float*)d_in[4];
  const float* bf = (const float*)d_in[5];
  const float* Ws = (const float*)d_in[6];
  const float* bs = (const float*)d_in[7];
  const float* bn_w = (const float*)d_in[8];
  const float* bn_b = (const float*)d_in[9];
  const float* ln_w = (const float*)d_in[10];
  const float* ln_b = (const float*)d_in[11];
  const float* Wl = (const float*)d_in[12];
  const float* bl = (const float*)d_in[13];
  const float* w4 = (const float*)d_in[14];
  const float* b4 = (const float*)d_in[15];

  const int N = in_sizes[0] / 64;
  const int E = in_sizes[2] / 32;
  const int G = 512;

  float* ws = (float*)d_ws;
  float* agg = ws;                                   // N*64
  int* offsets = (int*)(agg + (size_t)N * 64);       // N+4
  float* stats = (float*)(offsets + N + 4);          // 320   [zeroed]
  float* add_pool = stats + 320;                     // G*64  [zeroed]
  float* counts = add_pool + (size_t)G * 64;         // G     [zeroed]
  int* deg = (int*)(counts + G);                     // N     [zeroed]
  int* cursor = deg + N;                             // N
  float* ab = (float*)(cursor + N);                  // 132
  int2* epair = (int2*)(ab + 132);                   // E int2
  float* Pdst = (float*)((int*)epair + 2 * (size_t)E);  // N*128
  float* Psrc = Pdst + (size_t)N * 128;              // N*128

  size_t zeroFloats = 320 + (size_t)G * 64 + G + N;
  hipMemsetAsync(stats, 0, zeroFloats * sizeof(float), stream);

  node_gemm<<<2048, 256, 0, stream>>>(x, Wf, bf, Ws, bs, Pdst, Psrc, N);
  hist_kernel<<<(E + 255) / 256, 256, 0, stream>>>(ei, deg, E);
  scan_kernel<<<1, 1024, 0, stream>>>(deg, offsets, cursor, N);
  scatter_kernel<<<(E + 255) / 256, 256, 0, stream>>>(ei, cursor, epair, E);
  edge_agg<<<2048, 256, 0, stream>>>(offsets, epair, eattr, Wf, Ws, Pdst, Psrc,
                                     agg, N, 2048 * 4);
  stats_kernel<<<512, 256, 0, stream>>>(agg, x, stats, N);
  finalize_stats<<<1, 64, 0, stream>>>(stats, bn_w, bn_b, ab, N);
  const int chunk = (N + 511) / 512;
  node_finish<<<512, 256, 0, stream>>>(agg, x, batch, ab, ln_w, ln_b, add_pool,
                                       counts, N, chunk);
  graph_out<<<1, 1024, 0, stream>>>(add_pool, counts, Wl, bl, w4, b4,
                                    (float*)d_out, G);
}

// Round 5
// 368.390 us; speedup vs baseline: 1.1744x; 1.1744x over previous
//
#include <hip/hip_runtime.h>
#include <math.h>

#define EPSF 1e-5f

// ---------------- K1: node transforms  P = x @ {Wf_i, Ws_i, Wf_j, Ws_j} (+bias) ----
__global__ __launch_bounds__(256) void node_gemm(
    const float* __restrict__ x, const float* __restrict__ Wf,
    const float* __restrict__ bf, const float* __restrict__ Ws,
    const float* __restrict__ bs, float* __restrict__ Pdst,
    float* __restrict__ Psrc, int N) {
  const int lane = threadIdx.x & 63;
  const int w = threadIdx.x >> 6;
  const float* W = (w & 1) ? Ws : Wf;
  const int baseRow = (w >> 1) * 64;
  float wreg[64];
#pragma unroll
  for (int k = 0; k < 64; ++k) wreg[k] = W[(baseRow + k) * 64 + lane];
  float bias = 0.f;
  if (w == 0) bias = bf[lane];
  if (w == 1) bias = bs[lane];
  float* outp = (w >> 1) ? Psrc : Pdst;
  const int outOff = (w & 1) * 64;

  for (int n = blockIdx.x; n < N; n += gridDim.x) {
    const float* xr = x + (size_t)n * 64;
    float acc = bias;
#pragma unroll
    for (int k = 0; k < 64; k += 4) {
      float4 xv = *(const float4*)(xr + k);
      acc = fmaf(xv.x, wreg[k], acc);
      acc = fmaf(xv.y, wreg[k + 1], acc);
      acc = fmaf(xv.z, wreg[k + 2], acc);
      acc = fmaf(xv.w, wreg[k + 3], acc);
    }
    outp[(size_t)n * 128 + outOff + lane] = acc;
  }
}

// ---------------- Wprep: transpose edge-weight rows to [group][lane] float4 ----
__global__ __launch_bounds__(512) void wT_kernel(const float* __restrict__ Wf,
                                                 const float* __restrict__ Ws,
                                                 float4* __restrict__ WfT4,
                                                 float4* __restrict__ WsT4) {
  const int t = threadIdx.x, g = t >> 6, l = t & 63;
  const int k = 128 + 4 * g;
  WfT4[g * 64 + l] = make_float4(Wf[k * 64 + l], Wf[(k + 1) * 64 + l],
                                 Wf[(k + 2) * 64 + l], Wf[(k + 3) * 64 + l]);
  WsT4[g * 64 + l] = make_float4(Ws[k * 64 + l], Ws[(k + 1) * 64 + l],
                                 Ws[(k + 2) * 64 + l], Ws[(k + 3) * 64 + l]);
}

// ---------------- CSR build: histogram of dst ----------------
__global__ void hist_kernel(const int* __restrict__ ei, int* __restrict__ deg,
                            int E) {
  int i = blockIdx.x * blockDim.x + threadIdx.x;
  if (i < E) atomicAdd(&deg[ei[E + i]], 1);
}

// ---------------- CSR build: 3-phase parallel exclusive scan ----------------
__global__ __launch_bounds__(256) void scan_a(const int* __restrict__ deg,
                                              int* __restrict__ bsum, int N) {
  const int idx = blockIdx.x * 256 + threadIdx.x;
  int v = (idx < N) ? deg[idx] : 0;
#pragma unroll
  for (int o = 32; o > 0; o >>= 1) v += __shfl_down(v, o);
  __shared__ int ws4[4];
  if ((threadIdx.x & 63) == 0) ws4[threadIdx.x >> 6] = v;
  __syncthreads();
  if (threadIdx.x == 0) bsum[blockIdx.x] = ws4[0] + ws4[1] + ws4[2] + ws4[3];
}

__global__ __launch_bounds__(256) void scan_b(const int* __restrict__ bsum,
                                              int* __restrict__ bpre, int NB) {
  const int t = threadIdx.x;
  const int lane = t & 63, w = t >> 6;
  int v = (t < NB) ? bsum[t] : 0;
  int sc = v;
#pragma unroll
  for (int o = 1; o < 64; o <<= 1) {
    int u = __shfl_up(sc, o);
    if (lane >= o) sc += u;
  }
  __shared__ int wsum[4];
  if (lane == 63) wsum[w] = sc;
  __syncthreads();
  int add = 0;
#pragma unroll
  for (int k = 0; k < 4; ++k) add += (k < w) ? wsum[k] : 0;
  bpre[t] = (sc - v) + add;
}

__global__ __launch_bounds__(256) void scan_c(const int* __restrict__ deg,
                                              const int* __restrict__ bpre,
                                              int* __restrict__ offsets,
                                              int* __restrict__ cursor, int N) {
  const int t = threadIdx.x;
  const int lane = t & 63, w = t >> 6;
  const int idx = blockIdx.x * 256 + t;
  int d = (idx < N) ? deg[idx] : 0;
  int sc = d;
#pragma unroll
  for (int o = 1; o < 64; o <<= 1) {
    int u = __shfl_up(sc, o);
    if (lane >= o) sc += u;
  }
  __shared__ int wsum[4];
  if (lane == 63) wsum[w] = sc;
  __syncthreads();
  int add = bpre[blockIdx.x];
#pragma unroll
  for (int k = 0; k < 4; ++k) add += (k < w) ? wsum[k] : 0;
  const int off = add + (sc - d);
  if (idx < N) {
    offsets[idx] = off;
    cursor[idx] = off;
    if (idx == N - 1) offsets[N] = off + d;
  }
}

// ---------------- CSR build: scatter (eattr_idx, src) pairs -----------------
__global__ void scatter_kernel(const int* __restrict__ ei,
                               int* __restrict__ cursor,
                               int2* __restrict__ epair, int E) {
  int i = blockIdx.x * blockDim.x + threadIdx.x;
  if (i < E) {
    int dst = ei[E + i];
    int pos = atomicAdd(&cursor[dst], 1);
    epair[pos] = make_int2(i, ei[i]);
  }
}

// ---------------- K2: per-node edge aggregation (one wave per node) ----------
// Wave loads the node's entire epair run coalesced (lane j = edge j), then
// broadcasts each edge via readlane. Edge weights read as coalesced float4
// from the transposed copy (L1-hot / LICM-hoistable).
__global__ __launch_bounds__(256, 5) void edge_agg(
    const int* __restrict__ offsets, const int2* __restrict__ epair,
    const float* __restrict__ eattr, const float4* __restrict__ WfT4,
    const float4* __restrict__ WsT4, const float* __restrict__ Pdst,
    const float* __restrict__ Psrc, float* __restrict__ agg, int N) {
  const int lane = threadIdx.x & 63;
  const int n = blockIdx.x * 4 + (threadIdx.x >> 6);
  if (n >= N) return;
  const int o0 = offsets[n];
  const int o1 = offsets[n + 1];
  const float fb = Pdst[(size_t)n * 128 + lane];
  const float sb = Pdst[(size_t)n * 128 + 64 + lane];
  float acc = 0.f;
  for (int base = o0; base < o1; base += 64) {
    const int m = min(64, o1 - base);
    int2 p = make_int2(0, 0);
    if (lane < m) p = epair[base + lane];
    for (int j = 0; j < m; ++j) {
      const int ex = __builtin_amdgcn_readlane(p.x, j);
      const int sr = __builtin_amdgcn_readlane(p.y, j);
      const float* er = eattr + (size_t)ex * 32;
      const float* pr = Psrc + (size_t)sr * 128;
      float fA0 = fb + pr[lane], fA1 = 0.f, fA2 = 0.f, fA3 = 0.f;
      float sA0 = sb + pr[64 + lane], sA1 = 0.f, sA2 = 0.f, sA3 = 0.f;
#pragma unroll
      for (int g = 0; g < 8; g += 4) {
        float4 e0 = *(const float4*)(er + 4 * g);
        float4 e1 = *(const float4*)(er + 4 * g + 4);
        float4 e2 = *(const float4*)(er + 4 * g + 8);
        float4 e3 = *(const float4*)(er + 4 * g + 12);
        float4 w0 = WfT4[(g + 0) * 64 + lane];
        float4 w1 = WfT4[(g + 1) * 64 + lane];
        float4 w2 = WfT4[(g + 2) * 64 + lane];
        float4 w3 = WfT4[(g + 3) * 64 + lane];
        float4 v0 = WsT4[(g + 0) * 64 + lane];
        float4 v1 = WsT4[(g + 1) * 64 + lane];
        float4 v2 = WsT4[(g + 2) * 64 + lane];
        float4 v3 = WsT4[(g + 3) * 64 + lane];
        fA0 = fmaf(e0.x, w0.x, fA0); fA0 = fmaf(e0.y, w0.y, fA0);
        fA0 = fmaf(e0.z, w0.z, fA0); fA0 = fmaf(e0.w, w0.w, fA0);
        fA1 = fmaf(e1.x, w1.x, fA1); fA1 = fmaf(e1.y, w1.y, fA1);
        fA1 = fmaf(e1.z, w1.z, fA1); fA1 = fmaf(e1.w, w1.w, fA1);
        fA2 = fmaf(e2.x, w2.x, fA2); fA2 = fmaf(e2.y, w2.y, fA2);
        fA2 = fmaf(e2.z, w2.z, fA2); fA2 = fmaf(e2.w, w2.w, fA2);
        fA3 = fmaf(e3.x, w3.x, fA3); fA3 = fmaf(e3.y, w3.y, fA3);
        fA3 = fmaf(e3.z, w3.z, fA3); fA3 = fmaf(e3.w, w3.w, fA3);
        sA0 = fmaf(e0.x, v0.x, sA0); sA0 = fmaf(e0.y, v0.y, sA0);
        sA0 = fmaf(e0.z, v0.z, sA0); sA0 = fmaf(e0.w, v0.w, sA0);
        sA1 = fmaf(e1.x, v1.x, sA1); sA1 = fmaf(e1.y, v1.y, sA1);
        sA1 = fmaf(e1.z, v1.z, sA1); sA1 = fmaf(e1.w, v1.w, sA1);
        sA2 = fmaf(e2.x, v2.x, sA2); sA2 = fmaf(e2.y, v2.y, sA2);
        sA2 = fmaf(e2.z, v2.z, sA2); sA2 = fmaf(e2.w, v2.w, sA2);
        sA3 = fmaf(e3.x, v3.x, sA3); sA3 = fmaf(e3.y, v3.y, sA3);
        sA3 = fmaf(e3.z, v3.z, sA3); sA3 = fmaf(e3.w, v3.w, sA3);
      }
      float f = (fA0 + fA1) + (fA2 + fA3);
      float s = (sA0 + sA1) + (sA2 + sA3);
      float sig = __builtin_amdgcn_rcpf(1.0f + __expf(-f));
      float sp = fmaxf(s, 0.f) + __logf(1.0f + __expf(-fabsf(s)));
      acc += sig * sp;
    }
  }
  agg[(size_t)n * 64 + lane] = acc;
}

// ---------------- K3: per-feature reductions over agg and x ----------------
__global__ __launch_bounds__(256) void stats_kernel(
    const float* __restrict__ agg, const float* __restrict__ x,
    float* __restrict__ stats, int N) {
  const int f = threadIdx.x & 63;
  const int sub = threadIdx.x >> 6;
  float sa = 0, sa2 = 0, sx = 0, sx2 = 0, sax = 0;
  for (int r = blockIdx.x * 4 + sub; r < N; r += gridDim.x * 4) {
    float a = agg[(size_t)r * 64 + f];
    float xv = x[(size_t)r * 64 + f];
    sa += a; sa2 += a * a; sx += xv; sx2 += xv * xv; sax += a * xv;
  }
  __shared__ float lds[4][5][64];
  lds[sub][0][f] = sa; lds[sub][1][f] = sa2; lds[sub][2][f] = sx;
  lds[sub][3][f] = sx2; lds[sub][4][f] = sax;
  __syncthreads();
  if (sub == 0) {
#pragma unroll
    for (int i = 0; i < 5; ++i) {
      float v = lds[0][i][f] + lds[1][i][f] + lds[2][i][f] + lds[3][i][f];
      atomicAdd(&stats[i * 64 + f], v);
    }
  }
}

// ---------------- K4: finalize BN affine + analytic LN stats ----------------
__global__ __launch_bounds__(64) void finalize_stats(
    const float* __restrict__ stats, const float* __restrict__ bn_w,
    const float* __restrict__ bn_b, float* __restrict__ ab, int N) {
  const int f = threadIdx.x;
  const float Nf = (float)N;
  const float invN = 1.0f / Nf;
  float Sa = stats[f], Sa2 = stats[64 + f], Sx = stats[128 + f],
        Sx2 = stats[192 + f], Sax = stats[256 + f];
  float mu = Sa * invN;
  float var = Sa2 * invN - mu * mu;
  float alpha = bn_w[f] / sqrtf(var + EPSF);
  float beta = bn_b[f] - mu * alpha;
  float Sh = alpha * Sa + Nf * beta + Sx;
  float Sh2 = alpha * alpha * Sa2 + Sx2 + Nf * beta * beta +
              2.f * alpha * Sax + 2.f * alpha * beta * Sa + 2.f * beta * Sx;
#pragma unroll
  for (int o = 32; o > 0; o >>= 1) {
    Sh += __shfl_down(Sh, o);
    Sh2 += __shfl_down(Sh2, o);
  }
  ab[f] = alpha;
  ab[64 + f] = beta;
  if (f == 0) {
    float cnt = Nf * 64.0f;
    float mean = Sh / cnt;
    float msq = Sh2 / cnt - mean * mean;
    ab[128] = mean;
    ab[129] = 1.0f / (sqrtf(fmaxf(msq, 0.f)) + EPSF);
  }
}

// ---------------- K5: BN+residual+LN+softplus, pooled into graphs ------------
__global__ __launch_bounds__(256) void node_finish(
    const float* __restrict__ agg, const float* __restrict__ x,
    const int* __restrict__ batch, const float* __restrict__ ab,
    const float* __restrict__ ln_w, const float* __restrict__ ln_b,
    float* __restrict__ add_pool, float* __restrict__ counts, int N,
    int chunk) {
  const int f = threadIdx.x & 63;
  const int sub = threadIdx.x >> 6;
  const int r0 = blockIdx.x * chunk;
  const int r1 = min(N, r0 + chunk);
  const float alpha = ab[f], beta = ab[64 + f];
  const float mean = ab[128], rden = ab[129];
  const float lw = ln_w[f] * rden;
  const float lb = ln_b[f];
  float acc = 0.f, cacc = 0.f;
  int curg = -1;
  for (int r = r0 + sub; r < r1; r += 4) {
    int g = batch[r];
    if (g != curg) {
      if (curg >= 0) {
        atomicAdd(&add_pool[(size_t)curg * 64 + f], acc);
        if (f == 0) atomicAdd(&counts[curg], cacc);
      }
      curg = g; acc = 0.f; cacc = 0.f;
    }
    float h = fmaf(alpha, agg[(size_t)r * 64 + f], beta) + x[(size_t)r * 64 + f];
    float v = (h - mean) * lw + lb;
    float sp = fmaxf(v, 0.f) + __logf(1.0f + __expf(-fabsf(v)));
    acc += sp; cacc += 1.f;
  }
  if (curg >= 0) {
    atomicAdd(&add_pool[(size_t)curg * 64 + f], acc);
    if (f == 0) atomicAdd(&counts[curg], cacc);
  }
}

// ---------------- K6: graph head ----------------
__global__ __launch_bounds__(1024) void graph_out(
    const float* __restrict__ add_pool, const float* __restrict__ counts,
    const float* __restrict__ Wl, const float* __restrict__ bl,
    const float* __restrict__ w4, const float* __restrict__ b4,
    float* __restrict__ out, int G) {
  const int t = threadIdx.x;
  const int g = t >> 1, c = t & 1;
  float cnt = fmaxf(counts[g], 1.0f);
  float inv = 1.0f / cnt;
  const float* ap = add_pool + (size_t)g * 64;
  float v = bl[c];
#pragma unroll 8
  for (int k = 0; k < 64; ++k)
    v = fmaf(ap[k], fmaf(Wl[k * 2 + c], inv, Wl[(64 + k) * 2 + c]), v);

  __shared__ float red[16];
  __shared__ float bc[2];
  float sum = v;
#pragma unroll
  for (int o = 32; o > 0; o >>= 1) sum += __shfl_down(sum, o);
  if ((t & 63) == 0) red[t >> 6] = sum;
  __syncthreads();
  if (t == 0) {
    float tot = 0;
#pragma unroll
    for (int i = 0; i < 16; ++i) tot += red[i];
    bc[0] = tot * (1.0f / 1024.0f);
  }
  __syncthreads();
  const float mean = bc[0];
  const float xc = v - mean;
  float sq = xc * xc;
  __syncthreads();
#pragma unroll
  for (int o = 32; o > 0; o >>= 1) sq += __shfl_down(sq, o);
  if ((t & 63) == 0) red[t >> 6] = sq;
  __syncthreads();
  if (t == 0) {
    float tot = 0;
#pragma unroll
    for (int i = 0; i < 16; ++i) tot += red[i];
    bc[1] = 1.0f / (sqrtf(tot * (1.0f / 1024.0f)) + EPSF);
  }
  __syncthreads();
  out[t] = xc * bc[1] * w4[c] + b4[c];
}

extern "C" void kernel_launch(void* const* d_in, const int* in_sizes, int n_in,
                              void* d_out, int out_size, void* d_ws,
                              size_t ws_size, hipStream_t stream) {
  const float* x = (const float*)d_in[0];
  const int* ei = (const int*)d_in[1];
  const float* eattr = (const float*)d_in[2];
  const int* batch = (const int*)d_in[3];
  const float* Wf = (const float*)d_in[4];
  const float* bf = (const float*)d_in[5];
  const float* Ws = (const float*)d_in[6];
  const float* bs = (const float*)d_in[7];
  const float* bn_w = (const float*)d_in[8];
  const float* bn_b = (const float*)d_in[9];
  const float* ln_w = (const float*)d_in[10];
  const float* ln_b = (const float*)d_in[11];
  const float* Wl = (const float*)d_in[12];
  const float* bl = (const float*)d_in[13];
  const float* w4 = (const float*)d_in[14];
  const float* b4 = (const float*)d_in[15];

  const int N = in_sizes[0] / 64;
  const int E = in_sizes[2] / 32;
  const int G = 512;
  const int NB = (N + 255) / 256;

  // Workspace layout (all chunks multiple-of-4 elements => 16B alignment kept)
  float* ws = (float*)d_ws;
  float* agg = ws;                                   // N*64
  int* offsets = (int*)(agg + (size_t)N * 64);       // N+4
  float* stats = (float*)(offsets + N + 4);          // 320   [zeroed]
  float* add_pool = stats + 320;                     // G*64  [zeroed]
  float* counts = add_pool + (size_t)G * 64;         // G     [zeroed]
  int* deg = (int*)(counts + G);                     // N     [zeroed]
  int* cursor = deg + N;                             // N
  float* ab = (float*)(cursor + N);                  // 132
  int* bsum = (int*)(ab + 132);                      // 256
  int* bpre = bsum + 256;                            // 256
  float4* WfT4 = (float4*)(bpre + 256);              // 512 float4
  float4* WsT4 = WfT4 + 512;                         // 512 float4
  int2* epair = (int2*)(WsT4 + 512);                 // E int2
  float* Pdst = (float*)((int*)epair + 2 * (size_t)E);  // N*128
  float* Psrc = Pdst + (size_t)N * 128;              // N*128

  size_t zeroFloats = 320 + (size_t)G * 64 + G + N;
  hipMemsetAsync(stats, 0, zeroFloats * sizeof(float), stream);

  node_gemm<<<1024, 256, 0, stream>>>(x, Wf, bf, Ws, bs, Pdst, Psrc, N);
  wT_kernel<<<1, 512, 0, stream>>>(Wf, Ws, WfT4, WsT4);
  hist_kernel<<<(E + 255) / 256, 256, 0, stream>>>(ei, deg, E);
  scan_a<<<NB, 256, 0, stream>>>(deg, bsum, N);
  scan_b<<<1, 256, 0, stream>>>(bsum, bpre, NB);
  scan_c<<<NB, 256, 0, stream>>>(deg, bpre, offsets, cursor, N);
  scatter_kernel<<<(E + 255) / 256, 256, 0, stream>>>(ei, cursor, epair, E);
  edge_agg<<<(N + 3) / 4, 256, 0, stream>>>(offsets, epair, eattr, WfT4, WsT4,
                                            Pdst, Psrc, agg, N);
  stats_kernel<<<512, 256, 0, stream>>>(agg, x, stats, N);
  finalize_stats<<<1, 64, 0, stream>>>(stats, bn_w, bn_b, ab, N);
  const int chunk = (N + 511) / 512;
  node_finish<<<512, 256, 0, stream>>>(agg, x, batch, ab, ln_w, ln_b, add_pool,
                                       counts, N, chunk);
  graph_out<<<1, 1024, 0, stream>>>(add_pool, counts, Wl, bl, w4, b4,
                                    (float*)d_out, G);
}

// Round 6
// 332.523 us; speedup vs baseline: 1.3010x; 1.1079x over previous
//
#include <hip/hip_runtime.h>
#include <math.h>

#define EPSF 1e-5f

typedef short bf16x8 __attribute__((ext_vector_type(8)));
typedef float f32x4 __attribute__((ext_vector_type(4)));

static __device__ __forceinline__ unsigned short f2bf(float x) {
  unsigned u = __float_as_uint(x);
  unsigned r = (u + 0x7FFFu + ((u >> 16) & 1u)) >> 16;
  return (unsigned short)r;
}

// ---------------- K1: node transforms  P = x @ {Wf_i, Ws_i, Wf_j, Ws_j} (+bias) ----
__global__ __launch_bounds__(256) void node_gemm(
    const float* __restrict__ x, const float* __restrict__ Wf,
    const float* __restrict__ bf, const float* __restrict__ Ws,
    const float* __restrict__ bs, float* __restrict__ Pdst,
    float* __restrict__ Psrc, int N) {
  const int lane = threadIdx.x & 63;
  const int w = threadIdx.x >> 6;
  const float* W = (w & 1) ? Ws : Wf;
  const int baseRow = (w >> 1) * 64;
  float wreg[64];
#pragma unroll
  for (int k = 0; k < 64; ++k) wreg[k] = W[(baseRow + k) * 64 + lane];
  float bias = 0.f;
  if (w == 0) bias = bf[lane];
  if (w == 1) bias = bs[lane];
  float* outp = (w >> 1) ? Psrc : Pdst;
  const int outOff = (w & 1) * 64;

  for (int n = blockIdx.x; n < N; n += gridDim.x) {
    const float* xr = x + (size_t)n * 64;
    float acc = bias;
#pragma unroll
    for (int k = 0; k < 64; k += 4) {
      float4 xv = *(const float4*)(xr + k);
      acc = fmaf(xv.x, wreg[k], acc);
      acc = fmaf(xv.y, wreg[k + 1], acc);
      acc = fmaf(xv.z, wreg[k + 2], acc);
      acc = fmaf(xv.w, wreg[k + 3], acc);
    }
    outp[(size_t)n * 128 + outOff + lane] = acc;
  }
}

// ---------------- Prep: pack edge-part weights into MFMA B-fragment order ----
// B[k][n] for v_mfma_f32_16x16x32_bf16: lane l holds col n = (l&15), k = (l>>4)*8+i.
// 8 N-tiles: t8 0..3 -> lin_f cols t8*16+q ; t8 4..7 -> lin_s cols (t8-4)*16+q.
__global__ __launch_bounds__(512) void bfrag_kernel(
    const float* __restrict__ Wf, const float* __restrict__ Ws,
    unsigned short* __restrict__ Bfrag) {
  const int l = threadIdx.x & 63, t8 = threadIdx.x >> 6;
  const int q = l & 15, g = l >> 4;
  const float* W = (t8 < 4) ? Wf : Ws;
  const int col = (t8 & 3) * 16 + q;
  unsigned short out[8];
#pragma unroll
  for (int i = 0; i < 8; ++i)
    out[i] = f2bf(W[(size_t)(128 + g * 8 + i) * 64 + col]);
  *(uint4*)&Bfrag[((size_t)t8 * 64 + l) * 8] = *(uint4*)out;
}

// ---------------- CSR build: histogram of dst ----------------
__global__ void hist_kernel(const int* __restrict__ ei, int* __restrict__ deg,
                            int E) {
  int i = blockIdx.x * blockDim.x + threadIdx.x;
  if (i < E) atomicAdd(&deg[ei[E + i]], 1);
}

// ---------------- CSR build: 3-phase parallel exclusive scan ----------------
__global__ __launch_bounds__(256) void scan_a(const int* __restrict__ deg,
                                              int* __restrict__ bsum, int N) {
  const int idx = blockIdx.x * 256 + threadIdx.x;
  int v = (idx < N) ? deg[idx] : 0;
#pragma unroll
  for (int o = 32; o > 0; o >>= 1) v += __shfl_down(v, o);
  __shared__ int ws4[4];
  if ((threadIdx.x & 63) == 0) ws4[threadIdx.x >> 6] = v;
  __syncthreads();
  if (threadIdx.x == 0) bsum[blockIdx.x] = ws4[0] + ws4[1] + ws4[2] + ws4[3];
}

__global__ __launch_bounds__(256) void scan_b(const int* __restrict__ bsum,
                                              int* __restrict__ bpre, int NB) {
  const int t = threadIdx.x;
  const int lane = t & 63, w = t >> 6;
  int v = (t < NB) ? bsum[t] : 0;
  int sc = v;
#pragma unroll
  for (int o = 1; o < 64; o <<= 1) {
    int u = __shfl_up(sc, o);
    if (lane >= o) sc += u;
  }
  __shared__ int wsum[4];
  if (lane == 63) wsum[w] = sc;
  __syncthreads();
  int add = 0;
#pragma unroll
  for (int k = 0; k < 4; ++k) add += (k < w) ? wsum[k] : 0;
  bpre[t] = (sc - v) + add;
}

__global__ __launch_bounds__(256) void scan_c(const int* __restrict__ deg,
                                              const int* __restrict__ bpre,
                                              int* __restrict__ offsets,
                                              int* __restrict__ cursor, int N) {
  const int t = threadIdx.x;
  const int lane = t & 63, w = t >> 6;
  const int idx = blockIdx.x * 256 + t;
  int d = (idx < N) ? deg[idx] : 0;
  int sc = d;
#pragma unroll
  for (int o = 1; o < 64; o <<= 1) {
    int u = __shfl_up(sc, o);
    if (lane >= o) sc += u;
  }
  __shared__ int wsum[4];
  if (lane == 63) wsum[w] = sc;
  __syncthreads();
  int add = bpre[blockIdx.x];
#pragma unroll
  for (int k = 0; k < 4; ++k) add += (k < w) ? wsum[k] : 0;
  const int off = add + (sc - d);
  if (idx < N) {
    offsets[idx] = off;
    cursor[idx] = off;
    if (idx == N - 1) offsets[N] = off + d;
  }
}

// ---------------- CSR build: scatter (eattr_idx, src, dst) triples ------------
__global__ void scatter_kernel(const int* __restrict__ ei,
                               int* __restrict__ cursor,
                               int4* __restrict__ epair4, int E) {
  int i = blockIdx.x * blockDim.x + threadIdx.x;
  if (i < E) {
    int dst = ei[E + i];
    int pos = atomicAdd(&cursor[dst], 1);
    epair4[pos] = make_int4(i, ei[i], dst, 0);
  }
}

// ---------------- K2: MFMA edge kernel. One block = one 64-edge tile ----------
// A(64 edges x 32 eattr, bf16) @ B(32 x 128, bf16) via 4 waves x 8 mfma
// 16x16x32. C-layout (verified): col=lane&15, row=(lane>>4)*4+reg.
// Epilogue adds fp32 Pdst/Psrc gathers, sigmoid*softplus, segmented-reduce by
// dst run-id into LDS msum, then ~runs atomicAdd rows into agg.
__global__ __launch_bounds__(256) void edge_mfma(
    const int4* __restrict__ epair4, const float* __restrict__ eattr,
    const unsigned short* __restrict__ Bfrag, const float* __restrict__ Pdst,
    const float* __restrict__ Psrc, float* __restrict__ agg, int E, int N) {
  __shared__ __align__(16) unsigned short Ash[64 * 40];  // stride 40 bf16/row
  __shared__ __align__(16) int sd[128];                  // (src,dst) per edge
  __shared__ int eidx[64];
  __shared__ __align__(4) unsigned char ridb[64];
  __shared__ int rdst[64];
  __shared__ int nruns_s;
  __shared__ float msum[64][66];

  const int t = threadIdx.x, lane = t & 63, w = t >> 6;
  const int q = lane & 15, g = lane >> 4;
  const int base = blockIdx.x * 64;

  // ---- phase 0a (wave 0): load edge triples, run-id scan over sorted dst ----
  if (w == 0) {
    const int eg = base + lane;
    int4 p = make_int4(0, 0, 0, 0);
    if (eg < E) p = epair4[eg];
    const int valid = (eg < E);
    sd[lane * 2] = valid ? p.y : 0;       // src (clamped-safe)
    sd[lane * 2 + 1] = valid ? p.z : 0;   // dst
    eidx[lane] = valid ? p.x : 0;
    int d = valid ? p.z : 0x7FFFFFFF;     // sentinel run for invalid tail
    int dprev = __shfl_up(d, 1);
    int flag = (lane == 0 || d != dprev) ? 1 : 0;
    int sc = flag;
#pragma unroll
    for (int o = 1; o < 64; o <<= 1) {
      int u = __shfl_up(sc, o);
      if (lane >= o) sc += u;
    }
    int rid = sc - 1;
    ridb[lane] = (unsigned char)rid;
    if (flag) rdst[rid] = d;
    if (lane == 63) nruns_s = sc;
  }
  // ---- phase 0b: zero msum (all threads) ----
  for (int i = t; i < 64 * 66; i += 256) ((float*)msum)[i] = 0.f;
  __syncthreads();

  // ---- phase 1: stage A tile (gather eattr rows, convert bf16) ----
  {
    const int row = t >> 2, c = t & 3;
    const float* er = eattr + (size_t)eidx[row] * 32 + c * 8;
    float4 v0 = *(const float4*)er;
    float4 v1 = *(const float4*)(er + 4);
    bf16x8 sv;
    sv[0] = (short)f2bf(v0.x); sv[1] = (short)f2bf(v0.y);
    sv[2] = (short)f2bf(v0.z); sv[3] = (short)f2bf(v0.w);
    sv[4] = (short)f2bf(v1.x); sv[5] = (short)f2bf(v1.y);
    sv[6] = (short)f2bf(v1.z); sv[7] = (short)f2bf(v1.w);
    *(bf16x8*)&Ash[row * 40 + c * 8] = sv;
  }
  __syncthreads();

  // ---- phase 2: fragments + 8 MFMAs (wave w owns edges 16w..16w+15) ----
  union U { uint4 u; bf16x8 v; };
  bf16x8 b[8];
#pragma unroll
  for (int i = 0; i < 8; ++i) {
    U uu;
    uu.u = ((const uint4*)Bfrag)[i * 64 + lane];
    b[i] = uu.v;
  }
  const bf16x8 a = *(const bf16x8*)&Ash[(q + 16 * w) * 40 + g * 8];
  f32x4 acc[8];
#pragma unroll
  for (int i = 0; i < 8; ++i) {
    f32x4 z = {0.f, 0.f, 0.f, 0.f};
    acc[i] = __builtin_amdgcn_mfma_f32_16x16x32_bf16(a, b[i], z, 0, 0, 0);
  }

  // ---- phase 3: epilogue. Lane covers edges e=16w+g*4+reg, feats t8*16+q ----
  const int e0 = 16 * w + g * 4;
  int4 lo = *(const int4*)&sd[e0 * 2];        // s0,d0,s1,d1
  int4 hi = *(const int4*)&sd[e0 * 2 + 4];    // s2,d2,s3,d3
  const unsigned rid4 = *(const unsigned*)&ridb[e0];
  const float* pdp[4] = {Pdst + (size_t)lo.y * 128, Pdst + (size_t)lo.w * 128,
                         Pdst + (size_t)hi.y * 128, Pdst + (size_t)hi.w * 128};
  const float* psp[4] = {Psrc + (size_t)lo.x * 128, Psrc + (size_t)lo.z * 128,
                         Psrc + (size_t)hi.x * 128, Psrc + (size_t)hi.z * 128};
  const int r0 = rid4 & 255, r1 = (rid4 >> 8) & 255, r2 = (rid4 >> 16) & 255,
            r3 = (rid4 >> 24) & 255;

#pragma unroll
  for (int t8 = 0; t8 < 4; ++t8) {
    const int feat = t8 * 16 + q;
    float mm[4];
#pragma unroll
    for (int reg = 0; reg < 4; ++reg) {
      float Ff = acc[t8][reg] + pdp[reg][feat] + psp[reg][feat];
      float Fs = acc[t8 + 4][reg] + pdp[reg][64 + feat] + psp[reg][64 + feat];
      float sig = __builtin_amdgcn_rcpf(1.0f + __expf(-Ff));
      float sp = fmaxf(Fs, 0.f) + __logf(1.0f + __expf(-fabsf(Fs)));
      mm[reg] = sig * sp;
    }
    float a_ = mm[0];
    int cur = r0;
    if (r1 == cur) a_ += mm[1];
    else { atomicAdd(&msum[cur][feat], a_); cur = r1; a_ = mm[1]; }
    if (r2 == cur) a_ += mm[2];
    else { atomicAdd(&msum[cur][feat], a_); cur = r2; a_ = mm[2]; }
    if (r3 == cur) a_ += mm[3];
    else { atomicAdd(&msum[cur][feat], a_); cur = r3; a_ = mm[3]; }
    atomicAdd(&msum[cur][feat], a_);
  }
  __syncthreads();

  // ---- phase 4: flush runs to agg ----
  const int nr = nruns_s;
  for (int r = w; r < nr; r += 4) {
    const int dn = rdst[r];
    if (dn < N) atomicAdd(&agg[(size_t)dn * 64 + lane], msum[r][lane]);
  }
}

// ---------------- K3: per-feature reductions over agg and x ----------------
__global__ __launch_bounds__(256) void stats_kernel(
    const float* __restrict__ agg, const float* __restrict__ x,
    float* __restrict__ stats, int N) {
  const int f = threadIdx.x & 63;
  const int sub = threadIdx.x >> 6;
  float sa = 0, sa2 = 0, sx = 0, sx2 = 0, sax = 0;
  for (int r = blockIdx.x * 4 + sub; r < N; r += gridDim.x * 4) {
    float a = agg[(size_t)r * 64 + f];
    float xv = x[(size_t)r * 64 + f];
    sa += a; sa2 += a * a; sx += xv; sx2 += xv * xv; sax += a * xv;
  }
  __shared__ float lds[4][5][64];
  lds[sub][0][f] = sa; lds[sub][1][f] = sa2; lds[sub][2][f] = sx;
  lds[sub][3][f] = sx2; lds[sub][4][f] = sax;
  __syncthreads();
  if (sub == 0) {
#pragma unroll
    for (int i = 0; i < 5; ++i) {
      float v = lds[0][i][f] + lds[1][i][f] + lds[2][i][f] + lds[3][i][f];
      atomicAdd(&stats[i * 64 + f], v);
    }
  }
}

// ---------------- K4: finalize BN affine + analytic LN stats ----------------
__global__ __launch_bounds__(64) void finalize_stats(
    const float* __restrict__ stats, const float* __restrict__ bn_w,
    const float* __restrict__ bn_b, float* __restrict__ ab, int N) {
  const int f = threadIdx.x;
  const float Nf = (float)N;
  const float invN = 1.0f / Nf;
  float Sa = stats[f], Sa2 = stats[64 + f], Sx = stats[128 + f],
        Sx2 = stats[192 + f], Sax = stats[256 + f];
  float mu = Sa * invN;
  float var = Sa2 * invN - mu * mu;
  float alpha = bn_w[f] / sqrtf(var + EPSF);
  float beta = bn_b[f] - mu * alpha;
  float Sh = alpha * Sa + Nf * beta + Sx;
  float Sh2 = alpha * alpha * Sa2 + Sx2 + Nf * beta * beta +
              2.f * alpha * Sax + 2.f * alpha * beta * Sa + 2.f * beta * Sx;
#pragma unroll
  for (int o = 32; o > 0; o >>= 1) {
    Sh += __shfl_down(Sh, o);
    Sh2 += __shfl_down(Sh2, o);
  }
  ab[f] = alpha;
  ab[64 + f] = beta;
  if (f == 0) {
    float cnt = Nf * 64.0f;
    float mean = Sh / cnt;
    float msq = Sh2 / cnt - mean * mean;
    ab[128] = mean;
    ab[129] = 1.0f / (sqrtf(fmaxf(msq, 0.f)) + EPSF);
  }
}

// ---------------- K5: BN+residual+LN+softplus, pooled into graphs ------------
__global__ __launch_bounds__(256) void node_finish(
    const float* __restrict__ agg, const float* __restrict__ x,
    const int* __restrict__ batch, const float* __restrict__ ab,
    const float* __restrict__ ln_w, const float* __restrict__ ln_b,
    float* __restrict__ add_pool, float* __restrict__ counts, int N,
    int chunk) {
  const int f = threadIdx.x & 63;
  const int sub = threadIdx.x >> 6;
  const int r0 = blockIdx.x * chunk;
  const int r1 = min(N, r0 + chunk);
  const float alpha = ab[f], beta = ab[64 + f];
  const float mean = ab[128], rden = ab[129];
  const float lw = ln_w[f] * rden;
  const float lb = ln_b[f];
  float acc = 0.f, cacc = 0.f;
  int curg = -1;
  for (int r = r0 + sub; r < r1; r += 4) {
    int g = batch[r];
    if (g != curg) {
      if (curg >= 0) {
        atomicAdd(&add_pool[(size_t)curg * 64 + f], acc);
        if (f == 0) atomicAdd(&counts[curg], cacc);
      }
      curg = g; acc = 0.f; cacc = 0.f;
    }
    float h = fmaf(alpha, agg[(size_t)r * 64 + f], beta) + x[(size_t)r * 64 + f];
    float v = (h - mean) * lw + lb;
    float sp = fmaxf(v, 0.f) + __logf(1.0f + __expf(-fabsf(v)));
    acc += sp; cacc += 1.f;
  }
  if (curg >= 0) {
    atomicAdd(&add_pool[(size_t)curg * 64 + f], acc);
    if (f == 0) atomicAdd(&counts[curg], cacc);
  }
}

// ---------------- K6: graph head ----------------
__global__ __launch_bounds__(1024) void graph_out(
    const float* __restrict__ add_pool, const float* __restrict__ counts,
    const float* __restrict__ Wl, const float* __restrict__ bl,
    const float* __restrict__ w4, const float* __restrict__ b4,
    float* __restrict__ out, int G) {
  const int t = threadIdx.x;
  const int g = t >> 1, c = t & 1;
  float cnt = fmaxf(counts[g], 1.0f);
  float inv = 1.0f / cnt;
  const float* ap = add_pool + (size_t)g * 64;
  float v = bl[c];
#pragma unroll 8
  for (int k = 0; k < 64; ++k)
    v = fmaf(ap[k], fmaf(Wl[k * 2 + c], inv, Wl[(64 + k) * 2 + c]), v);

  __shared__ float red[16];
  __shared__ float bc[2];
  float sum = v;
#pragma unroll
  for (int o = 32; o > 0; o >>= 1) sum += __shfl_down(sum, o);
  if ((t & 63) == 0) red[t >> 6] = sum;
  __syncthreads();
  if (t == 0) {
    float tot = 0;
#pragma unroll
    for (int i = 0; i < 16; ++i) tot += red[i];
    bc[0] = tot * (1.0f / 1024.0f);
  }
  __syncthreads();
  const float mean = bc[0];
  const float xc = v - mean;
  float sq = xc * xc;
  __syncthreads();
#pragma unroll
  for (int o = 32; o > 0; o >>= 1) sq += __shfl_down(sq, o);
  if ((t & 63) == 0) red[t >> 6] = sq;
  __syncthreads();
  if (t == 0) {
    float tot = 0;
#pragma unroll
    for (int i = 0; i < 16; ++i) tot += red[i];
    bc[1] = 1.0f / (sqrtf(tot * (1.0f / 1024.0f)) + EPSF);
  }
  __syncthreads();
  out[t] = xc * bc[1] * w4[c] + b4[c];
}

extern "C" void kernel_launch(void* const* d_in, const int* in_sizes, int n_in,
                              void* d_out, int out_size, void* d_ws,
                              size_t ws_size, hipStream_t stream) {
  const float* x = (const float*)d_in[0];
  const int* ei = (const int*)d_in[1];
  const float* eattr = (const float*)d_in[2];
  const int* batch = (const int*)d_in[3];
  const float* Wf = (const float*)d_in[4];
  const float* bf = (const float*)d_in[5];
  const float* Ws = (const float*)d_in[6];
  const float* bs = (const float*)d_in[7];
  const float* bn_w = (const float*)d_in[8];
  const float* bn_b = (const float*)d_in[9];
  const float* ln_w = (const float*)d_in[10];
  const float* ln_b = (const float*)d_in[11];
  const float* Wl = (const float*)d_in[12];
  const float* bl = (const float*)d_in[13];
  const float* w4 = (const float*)d_in[14];
  const float* b4 = (const float*)d_in[15];

  const int N = in_sizes[0] / 64;
  const int E = in_sizes[2] / 32;
  const int G = 512;
  const int NB = (N + 255) / 256;
  const int T = (E + 63) / 64;

  // Workspace layout (elements; every chunk a multiple of 4 => 16B alignment)
  float* ws = (float*)d_ws;
  float* agg = ws;                                   // N*64   [zeroed]
  int* offsets = (int*)(agg + (size_t)N * 64);       // N+4
  float* stats = (float*)(offsets + N + 4);          // 320    [zeroed]
  float* add_pool = stats + 320;                     // G*64   [zeroed]
  float* counts = add_pool + (size_t)G * 64;         // G      [zeroed]
  int* deg = (int*)(counts + G);                     // N      [zeroed]
  int* cursor = deg + N;                             // N
  float* ab = (float*)(cursor + N);                  // 132
  int* bsum = (int*)(ab + 132);                      // 256
  int* bpre = bsum + 256;                            // 256
  unsigned short* Bfrag = (unsigned short*)(bpre + 256);  // 4096 ush = 2048 int
  int4* epair4 = (int4*)((int*)(bpre + 256) + 2048); // E int4
  float* Pdst = (float*)((int*)epair4 + 4 * (size_t)E);  // N*128
  float* Psrc = Pdst + (size_t)N * 128;              // N*128

  // zero agg..deg in one shot (offsets region overwritten by scan anyway)
  size_t zeroFloats =
      (size_t)N * 64 + (N + 4) + 320 + (size_t)G * 64 + G + N;
  hipMemsetAsync(agg, 0, zeroFloats * sizeof(float), stream);

  node_gemm<<<1024, 256, 0, stream>>>(x, Wf, bf, Ws, bs, Pdst, Psrc, N);
  bfrag_kernel<<<1, 512, 0, stream>>>(Wf, Ws, Bfrag);
  hist_kernel<<<(E + 255) / 256, 256, 0, stream>>>(ei, deg, E);
  scan_a<<<NB, 256, 0, stream>>>(deg, bsum, N);
  scan_b<<<1, 256, 0, stream>>>(bsum, bpre, NB);
  scan_c<<<NB, 256, 0, stream>>>(deg, bpre, offsets, cursor, N);
  scatter_kernel<<<(E + 255) / 256, 256, 0, stream>>>(ei, cursor, epair4, E);
  edge_mfma<<<T, 256, 0, stream>>>(epair4, eattr, Bfrag, Pdst, Psrc, agg, E, N);
  stats_kernel<<<512, 256, 0, stream>>>(agg, x, stats, N);
  finalize_stats<<<1, 64, 0, stream>>>(stats, bn_w, bn_b, ab, N);
  const int chunk = (N + 511) / 512;
  node_finish<<<512, 256, 0, stream>>>(agg, x, batch, ab, ln_w, ln_b, add_pool,
                                       counts, N, chunk);
  graph_out<<<1, 1024, 0, stream>>>(add_pool, counts, Wl, bl, w4, b4,
                                    (float*)d_out, G);
}